// Round 3
// baseline (504.529 us; speedup 1.0000x reference)
//
#include <hip/hip_runtime.h>
#include <math.h>

#define B_ 32
#define L_ 2049
#define E_ 1024
#define H_ 16
#define NT_ 8
#define STILE 256

// workspace layout (float offsets) — identical footprint to round 1 (known-safe)
#define OFF_Q     0
#define OFF_T     (OFF_Q + B_*E_)
#define OFF_QBK   (OFF_T + B_*H_*E_)
#define OFF_M     (OFF_QBK + B_*H_)
#define OFF_L     (OFF_M + B_*NT_*H_)
#define OFF_U     (OFF_L + B_*NT_*H_)
#define OFF_ATTN  (OFF_U + B_*H_*E_)
#define OFF_Y     (OFF_ATTN + B_*E_)
#define OFF_UP    (OFF_Y + B_*E_)

// ---------------------------------------------------------------- generic 32xE GEMM:
// C[b][j] = sum_k A[b*As + kbase + k] * W[j][k] + bias[j] (+ resid[b*Rs + j])
// mode 1 (vproj): kbase = (j>>6)*1024 (per-head slice of u). Grid: 512 blocks, j-tile=2.
__global__ __launch_bounds__(256) void k_gemm32(const float* __restrict__ A, long long As, int mode,
                                                const float* __restrict__ W,
                                                const float* __restrict__ bias,
                                                const float* __restrict__ resid, long long Rs,
                                                float* __restrict__ C) {
    __shared__ float wls[2 * 1056];  // 2 swizzled W rows
    const int j0 = blockIdx.x * 2, tid = threadIdx.x;
    #pragma unroll
    for (int k = 0; k < 2; ++k) {
        int idx4 = k * 256 + tid;
        int row = idx4 >> 8, c4 = idx4 & 255;
        float4 v = *(const float4*)(W + (size_t)(j0 + row) * E_ + 4 * c4);
        *(float4*)&wls[row * 1056 + 4 * c4 + ((c4 >> 5) << 2)] = v;  // swizzle: k + (k>>7)*4
    }
    __syncthreads();
    const int bb = tid >> 3, kseg = tid & 7;
    const long long kbase = (mode == 1) ? (long long)(j0 >> 6) * E_ : 0;
    const float* arow = A + (size_t)bb * As + kbase + kseg * 128;
    float a0 = 0.f, a1 = 0.f;
    #pragma unroll 4
    for (int i = 0; i < 32; ++i) {
        float4 av = *(const float4*)(arow + 4 * i);
        const float* wb = &wls[kseg * 132 + 4 * i];
        float4 w0 = *(const float4*)(wb);
        float4 w1 = *(const float4*)(wb + 1056);
        a0 += av.x * w0.x + av.y * w0.y + av.z * w0.z + av.w * w0.w;
        a1 += av.x * w1.x + av.y * w1.y + av.z * w1.z + av.w * w1.w;
    }
    #pragma unroll
    for (int off = 4; off; off >>= 1) {
        a0 += __shfl_down(a0, off, 8);
        a1 += __shfl_down(a1, off, 8);
    }
    if (kseg == 0) {
        float r0 = a0 + bias[j0], r1 = a1 + bias[j0 + 1];
        if (resid) {
            r0 += resid[(size_t)bb * Rs + j0];
            r1 += resid[(size_t)bb * Rs + j0 + 1];
        }
        C[(size_t)bb * E_ + j0] = r0;
        C[(size_t)bb * E_ + j0 + 1] = r1;
    }
}

// ---------------------------------------------------------------- t = 0.125*q_h@Wk_h ; qbk
// grid (16 h, 16 e-tiles of 64), 256 thr
__global__ __launch_bounds__(256) void k_tproj(const float* __restrict__ Wk,
                                               const float* __restrict__ bk,
                                               float* __restrict__ ws) {
    __shared__ float qs[64 * 33];   // [d][b]
    __shared__ float wls[64 * 68];  // [d][e] padded/aligned
    const int h = blockIdx.x, e0 = blockIdx.y * 64, tid = threadIdx.x;
    const float* q = ws + OFF_Q;
    #pragma unroll
    for (int k = 0; k < 8; ++k) {
        int idx = k * 256 + tid;
        int b = idx >> 6, d = idx & 63;
        qs[d * 33 + b] = q[(size_t)b * E_ + 64 * h + d];
    }
    #pragma unroll
    for (int k = 0; k < 4; ++k) {
        int idx4 = k * 256 + tid;
        int d = idx4 >> 4, c4 = idx4 & 15;
        float4 v = *(const float4*)(Wk + (size_t)(64 * h + d) * E_ + e0 + 4 * c4);
        *(float4*)&wls[d * 68 + 4 * c4] = v;
    }
    __syncthreads();
    const int el = tid & 63, bq8 = tid >> 6;
    float acc[8];
    #pragma unroll
    for (int i = 0; i < 8; ++i) acc[i] = 0.f;
    for (int d = 0; d < 64; ++d) {
        float wv = wls[d * 68 + el];
        #pragma unroll
        for (int i = 0; i < 8; ++i) acc[i] += qs[d * 33 + (bq8 * 8 + i)] * wv;
    }
    float* t = ws + OFF_T;
    #pragma unroll
    for (int i = 0; i < 8; ++i)
        t[((size_t)(bq8 * 8 + i) * H_ + h) * E_ + e0 + el] = acc[i] * 0.125f;
    if (e0 == 0 && tid < 32) {
        float s = 0.f;
        for (int d = 0; d < 64; ++d) s += qs[d * 33 + tid] * bk[64 * h + d];
        ws[OFF_QBK + tid * H_ + h] = s * 0.125f;
    }
}

// ---------------------------------------------------------------- fused scores/softmax/u_part
// 1024 threads (16 waves), 1 block/CU (LDS 83 KB), ~83 KB LDS.
// REGISTER BUDGET NOTE (rounds 1-2): with 1024-thread blocks the backend's default
// occupancy target budgeted 64 VGPR/wave (8 waves/EU) and spilled ~110-750 MB of
// scratch per dispatch (WRITE_SIZE 127-768 MB vs 17 MB intentional). LDS already
// caps this kernel at 1 block/CU = 4 waves/EU, so request exactly that:
// amdgpu_waves_per_eu(4,4) -> 512/4 = 128 VGPR budget. Phase-1 working set is
// ~90 VGPR, so this eliminates spills at zero occupancy cost.
__global__ __attribute__((amdgpu_waves_per_eu(4, 4)))
__launch_bounds__(1024) void k_attn_core(const float* __restrict__ x,
                                         float* __restrict__ ws) {
    const int tile = blockIdx.x, b = blockIdx.y, tid = threadIdx.x;
    const int s0t = tile * STILE;
    const float* tmat = ws + OFF_T + (size_t)b * H_ * E_;
    const float* xb = x + (size_t)(b * L_ + 1 + s0t) * E_;

    __shared__ float smem[16384];   // t[16][1024] | ph2: 2 bufs of 8x1024 | combine: 8x2x1024
    __shared__ float wl[256 * 16];  // hi-half partial scores, then softmax weights [s][h]
    __shared__ float pmax[128], psum[128], msh[16];

    const int lane = tid & 63, w = tid >> 6;
    const int g = lane & 3, ssub = lane >> 2;
    const int wlo = w & 7;
    const int ehalf = (w >> 3) * 512;      // phase-1 e-half owned by this wave group
    const int sA = 32 * wlo + ssub, sB = sA + 16;

    // ---- stage full t (16x1024 = 64 KB), straight copy ----
    #pragma unroll
    for (int k = 0; k < 4; ++k) {
        int idx4 = k * 1024 + tid;
        *(float4*)&smem[4 * idx4] = *(const float4*)(tmat + 4 * idx4);
    }
    __syncthreads();

    // ================= phase 1: partial scores (no barriers inside) =================
    float acc[16][2];
    #pragma unroll
    for (int h = 0; h < 16; ++h) { acc[h][0] = 0.f; acc[h][1] = 0.f; }

    {
        const float* xA = xb + (size_t)sA * E_ + ehalf + 8 * g;
        const float* xB = xb + (size_t)sB * E_ + ehalf + 8 * g;
        const float* tb = &smem[ehalf + 8 * g];
        for (int c = 0; c < 16; ++c) {
            float4 a0 = *(const float4*)(xA + 32 * c);
            float4 a1 = *(const float4*)(xA + 32 * c + 4);
            float4 b0 = *(const float4*)(xB + 32 * c);
            float4 b1 = *(const float4*)(xB + 32 * c + 4);
            #pragma unroll
            for (int h = 0; h < 16; ++h) {
                float4 t0 = *(const float4*)(tb + h * E_ + 32 * c);
                float4 t1 = *(const float4*)(tb + h * E_ + 32 * c + 4);
                acc[h][0] += t0.x * a0.x + t0.y * a0.y + t0.z * a0.z + t0.w * a0.w
                           + t1.x * a1.x + t1.y * a1.y + t1.z * a1.z + t1.w * a1.w;
                acc[h][1] += t0.x * b0.x + t0.y * b0.y + t0.z * b0.z + t0.w * b0.w
                           + t1.x * b1.x + t1.y * b1.y + t1.z * b1.z + t1.w * b1.w;
            }
        }
    }
    // reduce over the 4 e-column lanes (g) — all 4 g-dups end with the full sum
    #pragma unroll
    for (int h = 0; h < 16; ++h) {
        #pragma unroll
        for (int s = 0; s < 2; ++s) {
            float v = acc[h][s];
            v += __shfl_xor(v, 1, 64);
            v += __shfl_xor(v, 2, 64);
            acc[h][s] = v;
        }
    }
    // hi e-half waves deposit partials into wl (g-branch picks the h-quad; static reg idx)
    if (w >= 8) {
        if (g == 0) {
            *(float4*)&wl[sA * 16 + 0]  = make_float4(acc[0][0], acc[1][0], acc[2][0], acc[3][0]);
            *(float4*)&wl[sB * 16 + 0]  = make_float4(acc[0][1], acc[1][1], acc[2][1], acc[3][1]);
        } else if (g == 1) {
            *(float4*)&wl[sA * 16 + 4]  = make_float4(acc[4][0], acc[5][0], acc[6][0], acc[7][0]);
            *(float4*)&wl[sB * 16 + 4]  = make_float4(acc[4][1], acc[5][1], acc[6][1], acc[7][1]);
        } else if (g == 2) {
            *(float4*)&wl[sA * 16 + 8]  = make_float4(acc[8][0], acc[9][0], acc[10][0], acc[11][0]);
            *(float4*)&wl[sB * 16 + 8]  = make_float4(acc[8][1], acc[9][1], acc[10][1], acc[11][1]);
        } else {
            *(float4*)&wl[sA * 16 + 12] = make_float4(acc[12][0], acc[13][0], acc[14][0], acc[15][0]);
            *(float4*)&wl[sB * 16 + 12] = make_float4(acc[12][1], acc[13][1], acc[14][1], acc[15][1]);
        }
    }
    __syncthreads();  // E1: hi partials visible; smem (t) free from here on

    // ================= softmax partials (lo waves hold full scores) =================
    if (w < 8) {
        const float* qbkp = ws + OFF_QBK + b * H_;
        #pragma unroll
        for (int h = 0; h < 16; ++h) {
            float qb = qbkp[h];
            acc[h][0] += wl[sA * 16 + h] + qb;
            acc[h][1] += wl[sB * 16 + h] + qb;
        }
        #pragma unroll
        for (int h = 0; h < 16; ++h) {
            float v = fmaxf(acc[h][0], acc[h][1]);
            v = fmaxf(v, __shfl_xor(v, 4, 64));
            v = fmaxf(v, __shfl_xor(v, 8, 64));
            v = fmaxf(v, __shfl_xor(v, 16, 64));
            v = fmaxf(v, __shfl_xor(v, 32, 64));
            if (lane == 0) pmax[w * 16 + h] = v;
        }
    }
    __syncthreads();  // B1
    if (tid < 16) {
        float M = pmax[tid];
        #pragma unroll
        for (int q = 1; q < 8; ++q) M = fmaxf(M, pmax[q * 16 + tid]);
        msh[tid] = M;
        ws[OFF_M + (size_t)(b * NT_ + tile) * H_ + tid] = M;
    }
    __syncthreads();  // B2
    if (w < 8) {
        float ex0[16], ex1[16];
        #pragma unroll
        for (int h = 0; h < 16; ++h) {
            float M = msh[h];
            ex0[h] = __expf(acc[h][0] - M);
            ex1[h] = __expf(acc[h][1] - M);
        }
        if (g == 0) {
            *(float4*)&wl[sA * 16 + 0]  = make_float4(ex0[0], ex0[1], ex0[2], ex0[3]);
            *(float4*)&wl[sB * 16 + 0]  = make_float4(ex1[0], ex1[1], ex1[2], ex1[3]);
        } else if (g == 1) {
            *(float4*)&wl[sA * 16 + 4]  = make_float4(ex0[4], ex0[5], ex0[6], ex0[7]);
            *(float4*)&wl[sB * 16 + 4]  = make_float4(ex1[4], ex1[5], ex1[6], ex1[7]);
        } else if (g == 2) {
            *(float4*)&wl[sA * 16 + 8]  = make_float4(ex0[8], ex0[9], ex0[10], ex0[11]);
            *(float4*)&wl[sB * 16 + 8]  = make_float4(ex1[8], ex1[9], ex1[10], ex1[11]);
        } else {
            *(float4*)&wl[sA * 16 + 12] = make_float4(ex0[12], ex0[13], ex0[14], ex0[15]);
            *(float4*)&wl[sB * 16 + 12] = make_float4(ex1[12], ex1[13], ex1[14], ex1[15]);
        }
        #pragma unroll
        for (int h = 0; h < 16; ++h) {
            float v = ex0[h] + ex1[h];
            v += __shfl_xor(v, 4, 64);
            v += __shfl_xor(v, 8, 64);
            v += __shfl_xor(v, 16, 64);
            v += __shfl_xor(v, 32, 64);
            if (lane == 0) psum[w * 16 + h] = v;
        }
    }
    __syncthreads();  // B3: weights complete; smem fully free for phase-2 buffers
    if (tid < 16) {
        float Ls = 0.f;
        #pragma unroll
        for (int q = 0; q < 8; ++q) Ls += psum[q * 16 + tid];
        ws[OFF_L + (size_t)(b * NT_ + tile) * H_ + tid] = Ls;
    }

    // ================= phase 2: u_part[h][e] = sum_s w[s][h]*x[s][e] =================
    const int hp = w & 7, shalf = w >> 3;
    float4 accA[4], accB[4];
    #pragma unroll
    for (int j = 0; j < 4; ++j) {
        accA[j] = make_float4(0.f, 0.f, 0.f, 0.f);
        accB[j] = make_float4(0.f, 0.f, 0.f, 0.f);
    }
    const int r0 = tid >> 8, c4 = tid & 255;  // staging: 2 float4/thread per 8-row chunk
    float4 st0 = *(const float4*)(xb + (size_t)(r0)     * E_ + 4 * c4);
    float4 st1 = *(const float4*)(xb + (size_t)(r0 + 4) * E_ + 4 * c4);
    *(float4*)&smem[(r0)     * 1024 + 4 * c4] = st0;
    *(float4*)&smem[(r0 + 4) * 1024 + 4 * c4] = st1;
    for (int c = 0; c < 32; ++c) {
        __syncthreads();
        if (c + 1 < 32) {
            st0 = *(const float4*)(xb + (size_t)(8 * (c + 1) + r0)     * E_ + 4 * c4);
            st1 = *(const float4*)(xb + (size_t)(8 * (c + 1) + r0 + 4) * E_ + 4 * c4);
        }
        const float* A = &smem[(c & 1) * 8192];
        #pragma unroll
        for (int rr = 0; rr < 4; ++rr) {
            const int r = 4 * shalf + rr;
            float2 wv = *(const float2*)&wl[(8 * c + r) * 16 + 2 * hp];
            #pragma unroll
            for (int ej = 0; ej < 4; ++ej) {
                float4 xv = *(const float4*)&A[r * 1024 + 4 * lane + 256 * ej];
                accA[ej].x += wv.x * xv.x; accA[ej].y += wv.x * xv.y;
                accA[ej].z += wv.x * xv.z; accA[ej].w += wv.x * xv.w;
                accB[ej].x += wv.y * xv.x; accB[ej].y += wv.y * xv.y;
                accB[ej].z += wv.y * xv.z; accB[ej].w += wv.y * xv.w;
            }
        }
        if (c + 1 < 32) {
            float* D = &smem[((c + 1) & 1) * 8192];
            *(float4*)&D[(r0)     * 1024 + 4 * c4] = st0;
            *(float4*)&D[(r0 + 4) * 1024 + 4 * c4] = st1;
        }
    }
    __syncthreads();  // all chunk reads done before smem reuse for combine
    if (shalf == 1) {
        #pragma unroll
        for (int ej = 0; ej < 4; ++ej) {
            *(float4*)&smem[hp * 2048 +        4 * lane + 256 * ej] = accA[ej];
            *(float4*)&smem[hp * 2048 + 1024 + 4 * lane + 256 * ej] = accB[ej];
        }
    }
    __syncthreads();
    if (shalf == 0) {
        float* up = ws + OFF_UP + ((size_t)(b * NT_ + tile) * H_ + 2 * hp) * E_;
        #pragma unroll
        for (int ej = 0; ej < 4; ++ej) {
            float4 pA = *(const float4*)&smem[hp * 2048 +        4 * lane + 256 * ej];
            float4 pB = *(const float4*)&smem[hp * 2048 + 1024 + 4 * lane + 256 * ej];
            float4 oA = make_float4(accA[ej].x + pA.x, accA[ej].y + pA.y,
                                    accA[ej].z + pA.z, accA[ej].w + pA.w);
            float4 oB = make_float4(accB[ej].x + pB.x, accB[ej].y + pB.y,
                                    accB[ej].z + pB.z, accB[ej].w + pB.w);
            *(float4*)(up +       4 * lane + 256 * ej) = oA;
            *(float4*)(up + E_ +  4 * lane + 256 * ej) = oB;
        }
    }
}

// ---------------------------------------------------------------- combine partial tiles
__global__ __launch_bounds__(256) void k_combine(float* __restrict__ ws) {
    const int b = blockIdx.x, h = blockIdx.y, tid = threadIdx.x;
    float m[NT_], l[NT_], f[NT_];
    float M = -1e30f;
    #pragma unroll
    for (int tg = 0; tg < NT_; ++tg) {
        m[tg] = ws[OFF_M + (b * NT_ + tg) * H_ + h];
        l[tg] = ws[OFF_L + (b * NT_ + tg) * H_ + h];
        M = fmaxf(M, m[tg]);
    }
    float Ls = 0.f;
    #pragma unroll
    for (int tg = 0; tg < NT_; ++tg) {
        f[tg] = __expf(m[tg] - M);
        Ls += f[tg] * l[tg];
    }
    const float inv = 1.f / Ls;
    float4 a = make_float4(0.f, 0.f, 0.f, 0.f);
    #pragma unroll
    for (int tg = 0; tg < NT_; ++tg) {
        float4 v = *(const float4*)(ws + OFF_UP + (size_t)((b * NT_ + tg) * H_ + h) * E_ + 4 * tid);
        a.x += f[tg] * v.x; a.y += f[tg] * v.y; a.z += f[tg] * v.z; a.w += f[tg] * v.w;
    }
    a.x *= inv; a.y *= inv; a.z *= inv; a.w *= inv;
    *(float4*)(ws + OFF_U + (size_t)(b * H_ + h) * E_ + 4 * tid) = a;
}

// ---------------------------------------------------------------- LayerNorm -> out
__global__ __launch_bounds__(256) void k_ln(const float* __restrict__ ws,
                                            const float* __restrict__ g,
                                            const float* __restrict__ be,
                                            float* __restrict__ out) {
    const int b = blockIdx.x, tid = threadIdx.x;
    const float* y = ws + OFF_Y + (size_t)b * E_;
    float4 v = *(const float4*)(y + 4 * tid);
    float s = v.x + v.y + v.z + v.w;
    float s2 = v.x * v.x + v.y * v.y + v.z * v.z + v.w * v.w;
    for (int o = 32; o; o >>= 1) {
        s += __shfl_down(s, o, 64);
        s2 += __shfl_down(s2, o, 64);
    }
    __shared__ float rs[4], rs2[4];
    int ww = tid >> 6;
    if ((tid & 63) == 0) { rs[ww] = s; rs2[ww] = s2; }
    __syncthreads();
    float S = rs[0] + rs[1] + rs[2] + rs[3];
    float S2 = rs2[0] + rs2[1] + rs2[2] + rs2[3];
    float mean = S * (1.f / 1024.f);
    float var = S2 * (1.f / 1024.f) - mean * mean;
    float r = rsqrtf(var + 1e-5f);
    float4 gv = *(const float4*)(g + 4 * tid);
    float4 bb2 = *(const float4*)(be + 4 * tid);
    float4 o;
    o.x = (v.x - mean) * r * gv.x + bb2.x;
    o.y = (v.y - mean) * r * gv.y + bb2.y;
    o.z = (v.z - mean) * r * gv.z + bb2.z;
    o.w = (v.w - mean) * r * gv.w + bb2.w;
    *(float4*)(out + (size_t)b * E_ + 4 * tid) = o;
}

extern "C" void kernel_launch(void* const* d_in, const int* in_sizes, int n_in,
                              void* d_out, int out_size, void* d_ws, size_t ws_size,
                              hipStream_t stream) {
    const float* x  = (const float*)d_in[0];
    const float* Wq = (const float*)d_in[1];
    const float* bq = (const float*)d_in[2];
    const float* Wk = (const float*)d_in[3];
    const float* bk = (const float*)d_in[4];
    const float* Wv = (const float*)d_in[5];
    const float* bv = (const float*)d_in[6];
    const float* Wo = (const float*)d_in[7];
    const float* bo = (const float*)d_in[8];
    const float* g  = (const float*)d_in[9];
    const float* be = (const float*)d_in[10];
    float* ws = (float*)d_ws;
    float* out = (float*)d_out;

    // q = cls @ Wq^T + bq
    k_gemm32<<<512, 256, 0, stream>>>(x, (long long)L_ * E_, 0, Wq, bq, nullptr, 0, ws + OFF_Q);
    // t = 0.125 * q_h @ Wk_h ; qbk
    k_tproj<<<dim3(16, 16), 256, 0, stream>>>(Wk, bk, ws);
    // fused attention core (1024 threads, 16 waves/CU)
    k_attn_core<<<dim3(NT_, B_), 1024, 0, stream>>>(x, ws);
    // combine softmax tiles
    k_combine<<<dim3(B_, H_), 256, 0, stream>>>(ws);
    // attn = Wv_h @ u_h + bv   (per-head K slice of u)
    k_gemm32<<<512, 256, 0, stream>>>(ws + OFF_U, (long long)H_ * E_, 1, Wv, bv, nullptr, 0, ws + OFF_ATTN);
    // y = attn @ Wo^T + bo + cls
    k_gemm32<<<512, 256, 0, stream>>>(ws + OFF_ATTN, (long long)E_, 0, Wo, bo, x, (long long)L_ * E_, ws + OFF_Y);
    // LayerNorm
    k_ln<<<B_, 256, 0, stream>>>(ws, g, be, out);
}

// Round 4
// 489.059 us; speedup vs baseline: 1.0316x; 1.0316x over previous
//
#include <hip/hip_runtime.h>
#include <math.h>

#define B_ 32
#define L_ 2049
#define E_ 1024
#define H_ 16
#define NT_ 8
#define STILE 256

// workspace layout (float offsets) — identical footprint to round 1 (known-safe)
#define OFF_Q     0
#define OFF_T     (OFF_Q + B_*E_)
#define OFF_QBK   (OFF_T + B_*H_*E_)
#define OFF_M     (OFF_QBK + B_*H_)
#define OFF_L     (OFF_M + B_*NT_*H_)
#define OFF_U     (OFF_L + B_*NT_*H_)
#define OFF_ATTN  (OFF_U + B_*H_*E_)
#define OFF_Y     (OFF_ATTN + B_*E_)
#define OFF_UP    (OFF_Y + B_*E_)

// ---------------------------------------------------------------- generic 32xE GEMM:
// C[b][j] = sum_k A[b*As + kbase + k] * W[j][k] + bias[j] (+ resid[b*Rs + j])
// mode 1 (vproj): kbase = (j>>6)*1024 (per-head slice of u). Grid: 512 blocks, j-tile=2.
__global__ __launch_bounds__(256) void k_gemm32(const float* __restrict__ A, long long As, int mode,
                                                const float* __restrict__ W,
                                                const float* __restrict__ bias,
                                                const float* __restrict__ resid, long long Rs,
                                                float* __restrict__ C) {
    __shared__ float wls[2 * 1056];  // 2 swizzled W rows
    const int j0 = blockIdx.x * 2, tid = threadIdx.x;
    #pragma unroll
    for (int k = 0; k < 2; ++k) {
        int idx4 = k * 256 + tid;
        int row = idx4 >> 8, c4 = idx4 & 255;
        float4 v = *(const float4*)(W + (size_t)(j0 + row) * E_ + 4 * c4);
        *(float4*)&wls[row * 1056 + 4 * c4 + ((c4 >> 5) << 2)] = v;  // swizzle: k + (k>>7)*4
    }
    __syncthreads();
    const int bb = tid >> 3, kseg = tid & 7;
    const long long kbase = (mode == 1) ? (long long)(j0 >> 6) * E_ : 0;
    const float* arow = A + (size_t)bb * As + kbase + kseg * 128;
    float a0 = 0.f, a1 = 0.f;
    #pragma unroll 4
    for (int i = 0; i < 32; ++i) {
        float4 av = *(const float4*)(arow + 4 * i);
        const float* wb = &wls[kseg * 132 + 4 * i];
        float4 w0 = *(const float4*)(wb);
        float4 w1 = *(const float4*)(wb + 1056);
        a0 += av.x * w0.x + av.y * w0.y + av.z * w0.z + av.w * w0.w;
        a1 += av.x * w1.x + av.y * w1.y + av.z * w1.z + av.w * w1.w;
    }
    #pragma unroll
    for (int off = 4; off; off >>= 1) {
        a0 += __shfl_down(a0, off, 8);
        a1 += __shfl_down(a1, off, 8);
    }
    if (kseg == 0) {
        float r0 = a0 + bias[j0], r1 = a1 + bias[j0 + 1];
        if (resid) {
            r0 += resid[(size_t)bb * Rs + j0];
            r1 += resid[(size_t)bb * Rs + j0 + 1];
        }
        C[(size_t)bb * E_ + j0] = r0;
        C[(size_t)bb * E_ + j0 + 1] = r1;
    }
}

// ---------------------------------------------------------------- t = 0.125*q_h@Wk_h ; qbk
// grid (16 h, 16 e-tiles of 64), 256 thr
__global__ __launch_bounds__(256) void k_tproj(const float* __restrict__ Wk,
                                               const float* __restrict__ bk,
                                               float* __restrict__ ws) {
    __shared__ float qs[64 * 33];   // [d][b]
    __shared__ float wls[64 * 68];  // [d][e] padded/aligned
    const int h = blockIdx.x, e0 = blockIdx.y * 64, tid = threadIdx.x;
    const float* q = ws + OFF_Q;
    #pragma unroll
    for (int k = 0; k < 8; ++k) {
        int idx = k * 256 + tid;
        int b = idx >> 6, d = idx & 63;
        qs[d * 33 + b] = q[(size_t)b * E_ + 64 * h + d];
    }
    #pragma unroll
    for (int k = 0; k < 4; ++k) {
        int idx4 = k * 256 + tid;
        int d = idx4 >> 4, c4 = idx4 & 15;
        float4 v = *(const float4*)(Wk + (size_t)(64 * h + d) * E_ + e0 + 4 * c4);
        *(float4*)&wls[d * 68 + 4 * c4] = v;
    }
    __syncthreads();
    const int el = tid & 63, bq8 = tid >> 6;
    float acc[8];
    #pragma unroll
    for (int i = 0; i < 8; ++i) acc[i] = 0.f;
    for (int d = 0; d < 64; ++d) {
        float wv = wls[d * 68 + el];
        #pragma unroll
        for (int i = 0; i < 8; ++i) acc[i] += qs[d * 33 + (bq8 * 8 + i)] * wv;
    }
    float* t = ws + OFF_T;
    #pragma unroll
    for (int i = 0; i < 8; ++i)
        t[((size_t)(bq8 * 8 + i) * H_ + h) * E_ + e0 + el] = acc[i] * 0.125f;
    if (e0 == 0 && tid < 32) {
        float s = 0.f;
        for (int d = 0; d < 64; ++d) s += qs[d * 33 + tid] * bk[64 * h + d];
        ws[OFF_QBK + tid * H_ + h] = s * 0.125f;
    }
}

// ---------------------------------------------------------------- fused scores/softmax/u_part
// 1024 threads (16 waves), 1 block/CU (LDS ~83 KB).
// REGISTER BUDGET NOTE (rounds 1-3): for 1024-thread blocks the backend allocates a
// hard 64-VGPR budget (default, launch_bounds(1024,4) and amdgpu_waves_per_eu(4,4)
// all produced VGPR_Count=64 with ~110 MB/dispatch of scratch spill traffic).
// So the kernel is written to FIT 64 VGPRs: phase 1 uses a 16-float e-granule
// (one float4 per row / per head per iteration, live set ~56) and caps unrolling.
// Arithmetic, LDS bytes and global bytes are identical to the 32-float version.
__global__ __launch_bounds__(1024) void k_attn_core(const float* __restrict__ x,
                                                    float* __restrict__ ws) {
    const int tile = blockIdx.x, b = blockIdx.y, tid = threadIdx.x;
    const int s0t = tile * STILE;
    const float* tmat = ws + OFF_T + (size_t)b * H_ * E_;
    const float* xb = x + (size_t)(b * L_ + 1 + s0t) * E_;

    __shared__ float smem[16384];   // t[16][1024] | ph2: 2 bufs of 8x1024 | combine: 8x2x1024
    __shared__ float wl[256 * 16];  // hi-half partial scores, then softmax weights [s][h]
    __shared__ float pmax[128], psum[128], msh[16];

    const int lane = tid & 63, w = tid >> 6;
    const int g = lane & 3, ssub = lane >> 2;
    const int wlo = w & 7;
    const int ehalf = (w >> 3) * 512;      // phase-1 e-half owned by this wave group
    const int sA = 32 * wlo + ssub, sB = sA + 16;

    // ---- stage full t (16x1024 = 64 KB), straight copy ----
    #pragma unroll
    for (int k = 0; k < 4; ++k) {
        int idx4 = k * 1024 + tid;
        *(float4*)&smem[4 * idx4] = *(const float4*)(tmat + 4 * idx4);
    }
    __syncthreads();

    // ================= phase 1: partial scores (no barriers inside) =================
    float acc[16][2];
    #pragma unroll
    for (int h = 0; h < 16; ++h) { acc[h][0] = 0.f; acc[h][1] = 0.f; }

    {
        // each quad lane g covers e = ehalf + 16*c + 4*g .. +3  (union over g = full half)
        const float* xA = xb + (size_t)sA * E_ + ehalf + 4 * g;
        const float* xB = xb + (size_t)sB * E_ + ehalf + 4 * g;
        const float* tb = &smem[ehalf + 4 * g];
        #pragma unroll 2
        for (int c = 0; c < 32; ++c) {
            float4 a0 = *(const float4*)(xA + 16 * c);
            float4 b0 = *(const float4*)(xB + 16 * c);
            #pragma unroll
            for (int h = 0; h < 16; ++h) {
                float4 t0 = *(const float4*)(tb + h * E_ + 16 * c);
                acc[h][0] += t0.x * a0.x + t0.y * a0.y + t0.z * a0.z + t0.w * a0.w;
                acc[h][1] += t0.x * b0.x + t0.y * b0.y + t0.z * b0.z + t0.w * b0.w;
            }
        }
    }
    // reduce over the 4 e-column lanes (g) — all 4 g-dups end with the full sum
    #pragma unroll
    for (int h = 0; h < 16; ++h) {
        #pragma unroll
        for (int s = 0; s < 2; ++s) {
            float v = acc[h][s];
            v += __shfl_xor(v, 1, 64);
            v += __shfl_xor(v, 2, 64);
            acc[h][s] = v;
        }
    }
    // hi e-half waves deposit partials into wl (g-branch picks the h-quad; static reg idx)
    if (w >= 8) {
        if (g == 0) {
            *(float4*)&wl[sA * 16 + 0]  = make_float4(acc[0][0], acc[1][0], acc[2][0], acc[3][0]);
            *(float4*)&wl[sB * 16 + 0]  = make_float4(acc[0][1], acc[1][1], acc[2][1], acc[3][1]);
        } else if (g == 1) {
            *(float4*)&wl[sA * 16 + 4]  = make_float4(acc[4][0], acc[5][0], acc[6][0], acc[7][0]);
            *(float4*)&wl[sB * 16 + 4]  = make_float4(acc[4][1], acc[5][1], acc[6][1], acc[7][1]);
        } else if (g == 2) {
            *(float4*)&wl[sA * 16 + 8]  = make_float4(acc[8][0], acc[9][0], acc[10][0], acc[11][0]);
            *(float4*)&wl[sB * 16 + 8]  = make_float4(acc[8][1], acc[9][1], acc[10][1], acc[11][1]);
        } else {
            *(float4*)&wl[sA * 16 + 12] = make_float4(acc[12][0], acc[13][0], acc[14][0], acc[15][0]);
            *(float4*)&wl[sB * 16 + 12] = make_float4(acc[12][1], acc[13][1], acc[14][1], acc[15][1]);
        }
    }
    __syncthreads();  // E1: hi partials visible; smem (t) free from here on

    // ================= softmax partials (lo waves hold full scores) =================
    if (w < 8) {
        const float* qbkp = ws + OFF_QBK + b * H_;
        #pragma unroll
        for (int h = 0; h < 16; ++h) {
            float qb = qbkp[h];
            acc[h][0] += wl[sA * 16 + h] + qb;
            acc[h][1] += wl[sB * 16 + h] + qb;
        }
        #pragma unroll
        for (int h = 0; h < 16; ++h) {
            float v = fmaxf(acc[h][0], acc[h][1]);
            v = fmaxf(v, __shfl_xor(v, 4, 64));
            v = fmaxf(v, __shfl_xor(v, 8, 64));
            v = fmaxf(v, __shfl_xor(v, 16, 64));
            v = fmaxf(v, __shfl_xor(v, 32, 64));
            if (lane == 0) pmax[w * 16 + h] = v;
        }
    }
    __syncthreads();  // B1
    if (tid < 16) {
        float M = pmax[tid];
        #pragma unroll
        for (int q = 1; q < 8; ++q) M = fmaxf(M, pmax[q * 16 + tid]);
        msh[tid] = M;
        ws[OFF_M + (size_t)(b * NT_ + tile) * H_ + tid] = M;
    }
    __syncthreads();  // B2
    if (w < 8) {
        float ex0[16], ex1[16];
        #pragma unroll
        for (int h = 0; h < 16; ++h) {
            float M = msh[h];
            ex0[h] = __expf(acc[h][0] - M);
            ex1[h] = __expf(acc[h][1] - M);
        }
        if (g == 0) {
            *(float4*)&wl[sA * 16 + 0]  = make_float4(ex0[0], ex0[1], ex0[2], ex0[3]);
            *(float4*)&wl[sB * 16 + 0]  = make_float4(ex1[0], ex1[1], ex1[2], ex1[3]);
        } else if (g == 1) {
            *(float4*)&wl[sA * 16 + 4]  = make_float4(ex0[4], ex0[5], ex0[6], ex0[7]);
            *(float4*)&wl[sB * 16 + 4]  = make_float4(ex1[4], ex1[5], ex1[6], ex1[7]);
        } else if (g == 2) {
            *(float4*)&wl[sA * 16 + 8]  = make_float4(ex0[8], ex0[9], ex0[10], ex0[11]);
            *(float4*)&wl[sB * 16 + 8]  = make_float4(ex1[8], ex1[9], ex1[10], ex1[11]);
        } else {
            *(float4*)&wl[sA * 16 + 12] = make_float4(ex0[12], ex0[13], ex0[14], ex0[15]);
            *(float4*)&wl[sB * 16 + 12] = make_float4(ex1[12], ex1[13], ex1[14], ex1[15]);
        }
        #pragma unroll
        for (int h = 0; h < 16; ++h) {
            float v = ex0[h] + ex1[h];
            v += __shfl_xor(v, 4, 64);
            v += __shfl_xor(v, 8, 64);
            v += __shfl_xor(v, 16, 64);
            v += __shfl_xor(v, 32, 64);
            if (lane == 0) psum[w * 16 + h] = v;
        }
    }
    __syncthreads();  // B3: weights complete; smem fully free for phase-2 buffers
    if (tid < 16) {
        float Ls = 0.f;
        #pragma unroll
        for (int q = 0; q < 8; ++q) Ls += psum[q * 16 + tid];
        ws[OFF_L + (size_t)(b * NT_ + tile) * H_ + tid] = Ls;
    }

    // ================= phase 2: u_part[h][e] = sum_s w[s][h]*x[s][e] =================
    const int hp = w & 7, shalf = w >> 3;
    float4 accA[4], accB[4];
    #pragma unroll
    for (int j = 0; j < 4; ++j) {
        accA[j] = make_float4(0.f, 0.f, 0.f, 0.f);
        accB[j] = make_float4(0.f, 0.f, 0.f, 0.f);
    }
    const int r0 = tid >> 8, c4 = tid & 255;  // staging: 2 float4/thread per 8-row chunk
    float4 st0 = *(const float4*)(xb + (size_t)(r0)     * E_ + 4 * c4);
    float4 st1 = *(const float4*)(xb + (size_t)(r0 + 4) * E_ + 4 * c4);
    *(float4*)&smem[(r0)     * 1024 + 4 * c4] = st0;
    *(float4*)&smem[(r0 + 4) * 1024 + 4 * c4] = st1;
    for (int c = 0; c < 32; ++c) {
        __syncthreads();
        if (c + 1 < 32) {
            st0 = *(const float4*)(xb + (size_t)(8 * (c + 1) + r0)     * E_ + 4 * c4);
            st1 = *(const float4*)(xb + (size_t)(8 * (c + 1) + r0 + 4) * E_ + 4 * c4);
        }
        const float* A = &smem[(c & 1) * 8192];
        #pragma unroll
        for (int rr = 0; rr < 4; ++rr) {
            const int r = 4 * shalf + rr;
            float2 wv = *(const float2*)&wl[(8 * c + r) * 16 + 2 * hp];
            #pragma unroll
            for (int ej = 0; ej < 4; ++ej) {
                float4 xv = *(const float4*)&A[r * 1024 + 4 * lane + 256 * ej];
                accA[ej].x += wv.x * xv.x; accA[ej].y += wv.x * xv.y;
                accA[ej].z += wv.x * xv.z; accA[ej].w += wv.x * xv.w;
                accB[ej].x += wv.y * xv.x; accB[ej].y += wv.y * xv.y;
                accB[ej].z += wv.y * xv.z; accB[ej].w += wv.y * xv.w;
            }
        }
        if (c + 1 < 32) {
            float* D = &smem[((c + 1) & 1) * 8192];
            *(float4*)&D[(r0)     * 1024 + 4 * c4] = st0;
            *(float4*)&D[(r0 + 4) * 1024 + 4 * c4] = st1;
        }
    }
    __syncthreads();  // all chunk reads done before smem reuse for combine
    if (shalf == 1) {
        #pragma unroll
        for (int ej = 0; ej < 4; ++ej) {
            *(float4*)&smem[hp * 2048 +        4 * lane + 256 * ej] = accA[ej];
            *(float4*)&smem[hp * 2048 + 1024 + 4 * lane + 256 * ej] = accB[ej];
        }
    }
    __syncthreads();
    if (shalf == 0) {
        float* up = ws + OFF_UP + ((size_t)(b * NT_ + tile) * H_ + 2 * hp) * E_;
        #pragma unroll
        for (int ej = 0; ej < 4; ++ej) {
            float4 pA = *(const float4*)&smem[hp * 2048 +        4 * lane + 256 * ej];
            float4 pB = *(const float4*)&smem[hp * 2048 + 1024 + 4 * lane + 256 * ej];
            float4 oA = make_float4(accA[ej].x + pA.x, accA[ej].y + pA.y,
                                    accA[ej].z + pA.z, accA[ej].w + pA.w);
            float4 oB = make_float4(accB[ej].x + pB.x, accB[ej].y + pB.y,
                                    accB[ej].z + pB.z, accB[ej].w + pB.w);
            *(float4*)(up +       4 * lane + 256 * ej) = oA;
            *(float4*)(up + E_ +  4 * lane + 256 * ej) = oB;
        }
    }
}

// ---------------------------------------------------------------- combine partial tiles
__global__ __launch_bounds__(256) void k_combine(float* __restrict__ ws) {
    const int b = blockIdx.x, h = blockIdx.y, tid = threadIdx.x;
    float m[NT_], l[NT_], f[NT_];
    float M = -1e30f;
    #pragma unroll
    for (int tg = 0; tg < NT_; ++tg) {
        m[tg] = ws[OFF_M + (b * NT_ + tg) * H_ + h];
        l[tg] = ws[OFF_L + (b * NT_ + tg) * H_ + h];
        M = fmaxf(M, m[tg]);
    }
    float Ls = 0.f;
    #pragma unroll
    for (int tg = 0; tg < NT_; ++tg) {
        f[tg] = __expf(m[tg] - M);
        Ls += f[tg] * l[tg];
    }
    const float inv = 1.f / Ls;
    float4 a = make_float4(0.f, 0.f, 0.f, 0.f);
    #pragma unroll
    for (int tg = 0; tg < NT_; ++tg) {
        float4 v = *(const float4*)(ws + OFF_UP + (size_t)((b * NT_ + tg) * H_ + h) * E_ + 4 * tid);
        a.x += f[tg] * v.x; a.y += f[tg] * v.y; a.z += f[tg] * v.z; a.w += f[tg] * v.w;
    }
    a.x *= inv; a.y *= inv; a.z *= inv; a.w *= inv;
    *(float4*)(ws + OFF_U + (size_t)(b * H_ + h) * E_ + 4 * tid) = a;
}

// ---------------------------------------------------------------- LayerNorm -> out
__global__ __launch_bounds__(256) void k_ln(const float* __restrict__ ws,
                                            const float* __restrict__ g,
                                            const float* __restrict__ be,
                                            float* __restrict__ out) {
    const int b = blockIdx.x, tid = threadIdx.x;
    const float* y = ws + OFF_Y + (size_t)b * E_;
    float4 v = *(const float4*)(y + 4 * tid);
    float s = v.x + v.y + v.z + v.w;
    float s2 = v.x * v.x + v.y * v.y + v.z * v.z + v.w * v.w;
    for (int o = 32; o; o >>= 1) {
        s += __shfl_down(s, o, 64);
        s2 += __shfl_down(s2, o, 64);
    }
    __shared__ float rs[4], rs2[4];
    int ww = tid >> 6;
    if ((tid & 63) == 0) { rs[ww] = s; rs2[ww] = s2; }
    __syncthreads();
    float S = rs[0] + rs[1] + rs[2] + rs[3];
    float S2 = rs2[0] + rs2[1] + rs2[2] + rs2[3];
    float mean = S * (1.f / 1024.f);
    float var = S2 * (1.f / 1024.f) - mean * mean;
    float r = rsqrtf(var + 1e-5f);
    float4 gv = *(const float4*)(g + 4 * tid);
    float4 bb2 = *(const float4*)(be + 4 * tid);
    float4 o;
    o.x = (v.x - mean) * r * gv.x + bb2.x;
    o.y = (v.y - mean) * r * gv.y + bb2.y;
    o.z = (v.z - mean) * r * gv.z + bb2.z;
    o.w = (v.w - mean) * r * gv.w + bb2.w;
    *(float4*)(out + (size_t)b * E_ + 4 * tid) = o;
}

extern "C" void kernel_launch(void* const* d_in, const int* in_sizes, int n_in,
                              void* d_out, int out_size, void* d_ws, size_t ws_size,
                              hipStream_t stream) {
    const float* x  = (const float*)d_in[0];
    const float* Wq = (const float*)d_in[1];
    const float* bq = (const float*)d_in[2];
    const float* Wk = (const float*)d_in[3];
    const float* bk = (const float*)d_in[4];
    const float* Wv = (const float*)d_in[5];
    const float* bv = (const float*)d_in[6];
    const float* Wo = (const float*)d_in[7];
    const float* bo = (const float*)d_in[8];
    const float* g  = (const float*)d_in[9];
    const float* be = (const float*)d_in[10];
    float* ws = (float*)d_ws;
    float* out = (float*)d_out;

    // q = cls @ Wq^T + bq
    k_gemm32<<<512, 256, 0, stream>>>(x, (long long)L_ * E_, 0, Wq, bq, nullptr, 0, ws + OFF_Q);
    // t = 0.125 * q_h @ Wk_h ; qbk
    k_tproj<<<dim3(16, 16), 256, 0, stream>>>(Wk, bk, ws);
    // fused attention core (1024 threads, 16 waves/CU)
    k_attn_core<<<dim3(NT_, B_), 1024, 0, stream>>>(x, ws);
    // combine softmax tiles
    k_combine<<<dim3(B_, H_), 256, 0, stream>>>(ws);
    // attn = Wv_h @ u_h + bv   (per-head K slice of u)
    k_gemm32<<<512, 256, 0, stream>>>(ws + OFF_U, (long long)H_ * E_, 1, Wv, bv, nullptr, 0, ws + OFF_ATTN);
    // y = attn @ Wo^T + bo + cls
    k_gemm32<<<512, 256, 0, stream>>>(ws + OFF_ATTN, (long long)E_, 0, Wo, bo, x, (long long)L_ * E_, ws + OFF_Y);
    // LayerNorm
    k_ln<<<B_, 256, 0, stream>>>(ws, g, be, out);
}